// Round 1
// baseline (543.234 us; speedup 1.0000x reference)
//
#include <hip/hip_runtime.h>
#include <math.h>

#define DIMM 512
#define NB 8
#define QLEN 1024
#define KLEN 4096

typedef __attribute__((ext_vector_type(4))) float floatx4;
typedef __attribute__((ext_vector_type(8))) short short8;     // 8 bf16 (4 VGPRs) MFMA frag
typedef __attribute__((ext_vector_type(4))) unsigned short ushort4v;
typedef __attribute__((ext_vector_type(8))) unsigned short ushort8v;

// ---------- bf16 helpers (bit-level, RNE) ----------
static __device__ __forceinline__ unsigned short f2bf(float f) {
    unsigned u = __builtin_bit_cast(unsigned, f);
    u += 0x7FFFu + ((u >> 16) & 1u);
    return (unsigned short)(u >> 16);
}
static __device__ __forceinline__ float bf2f(unsigned short h) {
    unsigned u = ((unsigned)h) << 16;
    return __builtin_bit_cast(float, u);
}

// ---------- async global->LDS, 16B per lane ----------
static __device__ __forceinline__ void gload16(const unsigned short* g, unsigned short* l) {
    __builtin_amdgcn_global_load_lds(
        (__attribute__((address_space(1))) void*)const_cast<unsigned short*>(g),
        (__attribute__((address_space(3))) void*)l,
        16, 0, 0);
}

// ---------- prep: fp32 [R,512] -> bf16 [R,1024] = [hi | lo] ----------
__global__ __launch_bounds__(256) void split_k(const float* __restrict__ x,
                                               unsigned short* __restrict__ dst) {
    int idx = blockIdx.x * 256 + threadIdx.x;          // one float4 per thread
    float4 v = ((const float4*)x)[idx];
    int r = idx >> 7;                                  // 128 float4 per row (C=512)
    int c = (idx & 127) << 2;
    float f[4] = {v.x, v.y, v.z, v.w};
    ushort4v hi, lo;
#pragma unroll
    for (int e = 0; e < 4; ++e) {
        unsigned short h = f2bf(f[e]);
        hi[e] = h;
        lo[e] = f2bf(f[e] - bf2f(h));
    }
    unsigned short* row = dst + ((size_t)r << 10);     // row stride 1024
    *(ushort4v*)(row + c) = hi;
    *(ushort4v*)(row + 512 + c) = lo;
}

// ---------- prep: fp32 [R,C] -> bf16 at dst[r*ldd + off + c] ----------
__global__ __launch_bounds__(256) void conv_hi(const float* __restrict__ x,
                                               unsigned short* __restrict__ dst,
                                               int c4shift, int ldd, int off) {
    int idx = blockIdx.x * 256 + threadIdx.x;
    float4 v = ((const float4*)x)[idx];
    int r = idx >> c4shift;
    int c = (idx & ((1 << c4shift) - 1)) << 2;
    ushort4v hi;
    hi[0] = f2bf(v.x); hi[1] = f2bf(v.y); hi[2] = f2bf(v.z); hi[3] = f2bf(v.w);
    *(ushort4v*)(dst + (size_t)r * ldd + off + c) = hi;
}

// ---------- prep: context [b,4096,512] fp32 -> ctxT [b,512,4096] bf16 (hi) ----------
__global__ __launch_bounds__(256) void trans_hi(const float* __restrict__ ctx,
                                                unsigned short* __restrict__ ctxT) {
    __shared__ unsigned short tile[64][66];            // +2 pad: spread banks
    int b = blockIdx.z;
    int c0 = blockIdx.x * 64;                          // dim index
    int k0 = blockIdx.y * 64;                          // seq index
    const float* src = ctx + ((size_t)b * KLEN + k0) * DIMM + c0;
    int t = threadIdx.x;
    int rr = t >> 4, cc4 = (t & 15) * 4;
#pragma unroll
    for (int it = 0; it < 4; ++it) {
        int r = rr + it * 16;
        float4 v = *(const float4*)(src + (size_t)r * DIMM + cc4);
        tile[r][cc4 + 0] = f2bf(v.x);
        tile[r][cc4 + 1] = f2bf(v.y);
        tile[r][cc4 + 2] = f2bf(v.z);
        tile[r][cc4 + 3] = f2bf(v.w);
    }
    __syncthreads();
#pragma unroll
    for (int it = 0; it < 2; ++it) {
        int u = t + it * 256;
        int c = u >> 3;                                // 0..63 (dim within tile)
        int kk = (u & 7) * 8;                          // 16B chunk along k
        ushort8v o;
#pragma unroll
        for (int e = 0; e < 8; ++e) o[e] = tile[kk + e][c];
        *(ushort8v*)(ctxT + ((size_t)b * DIMM + c0 + c) * KLEN + k0 + kk) = o;
    }
}

// ---------- softmax over rows of 4096: fp32 in-place + bf16 copy ----------
__global__ __launch_bounds__(256) void softmax_k(float* __restrict__ S,
                                                 unsigned short* __restrict__ Pb) {
    size_t row = blockIdx.x;
    float* p = S + row * KLEN;
    int t = threadIdx.x;
    int lane = t & 63, wv = t >> 6;
    float4 v[4];
    float mx = -3.0e38f;
#pragma unroll
    for (int i = 0; i < 4; ++i) {
        v[i] = *(const float4*)(p + i * 1024 + t * 4);
        mx = fmaxf(mx, fmaxf(fmaxf(v[i].x, v[i].y), fmaxf(v[i].z, v[i].w)));
    }
#pragma unroll
    for (int m = 32; m >= 1; m >>= 1) mx = fmaxf(mx, __shfl_xor(mx, m, 64));
    __shared__ float redm[4], reds[4];
    if (lane == 0) redm[wv] = mx;
    __syncthreads();
    mx = fmaxf(fmaxf(redm[0], redm[1]), fmaxf(redm[2], redm[3]));
    float sum = 0.f;
#pragma unroll
    for (int i = 0; i < 4; ++i) {
        v[i].x = __expf(v[i].x - mx); v[i].y = __expf(v[i].y - mx);
        v[i].z = __expf(v[i].z - mx); v[i].w = __expf(v[i].w - mx);
        sum += v[i].x + v[i].y + v[i].z + v[i].w;
    }
#pragma unroll
    for (int m = 32; m >= 1; m >>= 1) sum += __shfl_xor(sum, m, 64);
    if (lane == 0) reds[wv] = sum;
    __syncthreads();
    float inv = 1.0f / (reds[0] + reds[1] + reds[2] + reds[3]);
    unsigned short* pb = Pb + row * KLEN;
#pragma unroll
    for (int i = 0; i < 4; ++i) {
        float4 w;
        w.x = v[i].x * inv; w.y = v[i].y * inv; w.z = v[i].z * inv; w.w = v[i].w * inv;
        *(float4*)(p + i * 1024 + t * 4) = w;
        ushort4v h;
        h[0] = f2bf(w.x); h[1] = f2bf(w.y); h[2] = f2bf(w.z); h[3] = f2bf(w.w);
        *(ushort4v*)(pb + i * 1024 + t * 4) = h;
    }
}

// ---------- generic C = A * B^T GEMM (both operands K-major bf16), fp32 acc ----------
// 128x128 tile, BK=64, 4 waves in 2x2, each wave 4x4 MFMA 16x16x32 frags.
// EPI: 0 = store fp32; 1 = store bf16; 2 = tanh(x + bias[col]) fp32
// REMAP: QK split-bf16 virtual K=1536 over A=[Ah|Al](K=1024), B=[Bh|Bl](K=1024):
//   panels (Ah*Bh)+(Ah*Bl)+(Al*Bh)
template <int EPI, bool REMAP>
__global__ __launch_bounds__(256) void gemm_bt(
    const unsigned short* __restrict__ A,
    const unsigned short* __restrict__ Bm,
    float* __restrict__ Cf, unsigned short* __restrict__ Cb,
    const float* __restrict__ bias,
    int Ktiles, long lda, long ldb, long ldc,
    long a_bs, long b_bs, long c_bs) {
    __shared__ unsigned short sA[128 * 64];
    __shared__ unsigned short sB[128 * 64];
    const int tid = threadIdx.x;
    const int lane = tid & 63;
    const int wv = tid >> 6;
    const int wm = wv >> 1, wn = wv & 1;
    const int mlane = lane & 15, quad = lane >> 4;
    const unsigned short* Ab = A + (size_t)blockIdx.z * a_bs + (size_t)blockIdx.y * 128 * lda;
    const unsigned short* Bb = Bm + (size_t)blockIdx.z * b_bs + (size_t)blockIdx.x * 128 * ldb;
    const int r8 = tid >> 3;          // 0..31: row within staging pass
    const int c8 = (tid & 7) << 3;    // 16B chunk along K
    unsigned short* la = sA + r8 * 64 + c8;
    unsigned short* lb = sB + r8 * 64 + c8;

    floatx4 acc[4][4] = {};

    for (int kt = 0; kt < Ktiles; ++kt) {
        long kv = (long)kt * 64;
        long ka = REMAP ? (kv >= 512 ? kv - 512 : kv) : kv;
        long kb = REMAP ? (kv >= 1024 ? kv - 1024 : kv) : kv;
        if (kt) __syncthreads();                       // protect LDS from overwrite
        const unsigned short* ga = Ab + (size_t)r8 * lda + ka + c8;
        const unsigned short* gb = Bb + (size_t)r8 * ldb + kb + c8;
#pragma unroll
        for (int it = 0; it < 4; ++it) {
            gload16(ga + (size_t)(it * 32) * lda, la + it * 2048);
            gload16(gb + (size_t)(it * 32) * ldb, lb + it * 2048);
        }
        __syncthreads();                               // drains vmcnt before barrier
#pragma unroll
        for (int s = 0; s < 2; ++s) {
            short8 af[4], bf[4];
#pragma unroll
            for (int i = 0; i < 4; ++i)
                af[i] = *(const short8*)(sA + (wm * 64 + i * 16 + mlane) * 64 + s * 32 + quad * 8);
#pragma unroll
            for (int j = 0; j < 4; ++j)
                bf[j] = *(const short8*)(sB + (wn * 64 + j * 16 + mlane) * 64 + s * 32 + quad * 8);
#pragma unroll
            for (int i = 0; i < 4; ++i)
#pragma unroll
                for (int j = 0; j < 4; ++j)
                    acc[i][j] = __builtin_amdgcn_mfma_f32_16x16x32_bf16(af[i], bf[j], acc[i][j], 0, 0, 0);
        }
    }

    // epilogue: C/D layout col=lane&15, row=quad*4+reg
    size_t crow0 = (size_t)blockIdx.y * 128 + wm * 64 + quad * 4;
    size_t ccol0 = (size_t)blockIdx.x * 128 + wn * 64 + mlane;
    size_t cbase = (size_t)blockIdx.z * c_bs;
#pragma unroll
    for (int i = 0; i < 4; ++i) {
#pragma unroll
        for (int j = 0; j < 4; ++j) {
            size_t gr = crow0 + i * 16;
            size_t gc = ccol0 + j * 16;
#pragma unroll
            for (int r = 0; r < 4; ++r) {
                float vv = acc[i][j][r];
                size_t off = cbase + (gr + r) * ldc + gc;
                if (EPI == 0) Cf[off] = vv;
                else if (EPI == 1) Cb[off] = f2bf(vv);
                else Cf[off] = tanhf(vv + bias[gc]);
            }
        }
    }
}

extern "C" void kernel_launch(void* const* d_in, const int* in_sizes, int n_in,
                              void* d_out, int out_size, void* d_ws, size_t ws_size,
                              hipStream_t stream) {
    (void)in_sizes; (void)n_in; (void)out_size; (void)ws_size;
    const float* outp = (const float*)d_in[0];   // [8,1024,512]
    const float* ctx  = (const float*)d_in[1];   // [8,4096,512]
    const float* W    = (const float*)d_in[2];   // [512,1024]  (already K-major for C=A*W^T)
    const float* bias = (const float*)d_in[3];   // [512]

    float* out0 = (float*)d_out;                              // [8,1024,512]
    float* attn = out0 + (size_t)NB * QLEN * DIMM;            // [8,1024,4096]

    unsigned char* w = (unsigned char*)d_ws;
    // Region plan (113 MiB peak, time-aliased):
    //   R1 (16 MiB): A2 = [outHi|outLo]          -> later: combined [mix | outHi]
    //   R2 (64 MiB): B2 = [ctxHi|ctxLo]          -> later: attn bf16
    //   R3 (32 MiB): ctxT hi bf16 [b,512,4096]
    //   R4 ( 1 MiB): W bf16
    unsigned short* R1 = (unsigned short*)(w);
    unsigned short* R2 = (unsigned short*)(w + (16ull << 20));
    unsigned short* R3 = (unsigned short*)(w + (80ull << 20));
    unsigned short* R4 = (unsigned short*)(w + (112ull << 20));

    // 1. prep
    split_k<<<4096, 256, 0, stream>>>(outp, R1);                     // output -> A2
    split_k<<<16384, 256, 0, stream>>>(ctx, R2);                     // context -> B2
    trans_hi<<<dim3(8, 64, 8), 256, 0, stream>>>(ctx, R3);           // context -> ctxT hi
    conv_hi<<<512, 256, 0, stream>>>(W, R4, 8, 1024, 0);             // W -> bf16

    // 2. QK^T split-bf16 (virtual K=1536) -> raw logits in attn region
    gemm_bt<0, true><<<dim3(32, 8, 8), 256, 0, stream>>>(
        R1, R2, attn, nullptr, nullptr,
        24, 1024, 1024, 4096,
        (long)QLEN * 1024, (long)KLEN * 1024, (long)QLEN * KLEN);

    // 3. softmax rows: fp32 in-place + bf16 copy into R2 (B2 is dead)
    softmax_k<<<8192, 256, 0, stream>>>(attn, R2);

    // 4a. combined[:,512:] = outHi (R1's A2 is dead; rebuild as combined)
    conv_hi<<<4096, 256, 0, stream>>>(outp, R1, 7, 1024, 512);

    // 4b. PV: mix = attn_bf16 * ctxT^T -> combined[:,0:512] (bf16)
    gemm_bt<1, false><<<dim3(4, 8, 8), 256, 0, stream>>>(
        R2, R3, nullptr, R1, nullptr,
        64, 4096, 4096, 1024,
        (long)QLEN * KLEN, (long)DIMM * KLEN, (long)QLEN * 1024);

    // 5. out = tanh(combined * W^T + b)
    gemm_bt<2, false><<<dim3(4, 64, 1), 256, 0, stream>>>(
        R1, R4, out0, nullptr, bias,
        16, 1024, 1024, 512, 0, 0, 0);
}

// Round 2
// 505.503 us; speedup vs baseline: 1.0746x; 1.0746x over previous
//
#include <hip/hip_runtime.h>
#include <math.h>

#define DIMM 512
#define NB 8
#define QLEN 1024
#define KLEN 4096

typedef __attribute__((ext_vector_type(4))) float floatx4;
typedef __attribute__((ext_vector_type(8))) short short8;     // 8 bf16 (4 VGPRs) MFMA frag
typedef __attribute__((ext_vector_type(4))) unsigned short ushort4v;
typedef __attribute__((ext_vector_type(8))) unsigned short ushort8v;

// ---------- bf16 helpers (bit-level, RNE) ----------
static __device__ __forceinline__ unsigned short f2bf(float f) {
    unsigned u = __builtin_bit_cast(unsigned, f);
    u += 0x7FFFu + ((u >> 16) & 1u);
    return (unsigned short)(u >> 16);
}
static __device__ __forceinline__ float bf2f(unsigned short h) {
    unsigned u = ((unsigned)h) << 16;
    return __builtin_bit_cast(float, u);
}

// ---------- async global->LDS, 16B per lane ----------
static __device__ __forceinline__ void gload16(const unsigned short* g, unsigned short* l) {
    __builtin_amdgcn_global_load_lds(
        (__attribute__((address_space(1))) void*)const_cast<unsigned short*>(g),
        (__attribute__((address_space(3))) void*)l,
        16, 0, 0);
}

// ---------- prep: fp32 [R,512] -> bf16 [R,1024] = [hi | lo] ----------
__global__ __launch_bounds__(256) void split_k(const float* __restrict__ x,
                                               unsigned short* __restrict__ dst) {
    int idx = blockIdx.x * 256 + threadIdx.x;          // one float4 per thread
    float4 v = ((const float4*)x)[idx];
    int r = idx >> 7;                                  // 128 float4 per row (C=512)
    int c = (idx & 127) << 2;
    float f[4] = {v.x, v.y, v.z, v.w};
    ushort4v hi, lo;
#pragma unroll
    for (int e = 0; e < 4; ++e) {
        unsigned short h = f2bf(f[e]);
        hi[e] = h;
        lo[e] = f2bf(f[e] - bf2f(h));
    }
    unsigned short* row = dst + ((size_t)r << 10);     // row stride 1024
    *(ushort4v*)(row + c) = hi;
    *(ushort4v*)(row + 512 + c) = lo;
}

// ---------- prep: fp32 [R,C] -> bf16 at dst[r*ldd + off + c] ----------
__global__ __launch_bounds__(256) void conv_hi(const float* __restrict__ x,
                                               unsigned short* __restrict__ dst,
                                               int c4shift, int ldd, int off) {
    int idx = blockIdx.x * 256 + threadIdx.x;
    float4 v = ((const float4*)x)[idx];
    int r = idx >> c4shift;
    int c = (idx & ((1 << c4shift) - 1)) << 2;
    ushort4v hi;
    hi[0] = f2bf(v.x); hi[1] = f2bf(v.y); hi[2] = f2bf(v.z); hi[3] = f2bf(v.w);
    *(ushort4v*)(dst + (size_t)r * ldd + off + c) = hi;
}

// ---------- prep: context [b,4096,512] fp32 -> ctxT [b,512,4096] bf16 (hi) ----------
__global__ __launch_bounds__(256) void trans_hi(const float* __restrict__ ctx,
                                                unsigned short* __restrict__ ctxT) {
    __shared__ unsigned short tile[64][66];            // +2 pad: spread banks
    int b = blockIdx.z;
    int c0 = blockIdx.x * 64;                          // dim index
    int k0 = blockIdx.y * 64;                          // seq index
    const float* src = ctx + ((size_t)b * KLEN + k0) * DIMM + c0;
    int t = threadIdx.x;
    int rr = t >> 4, cc4 = (t & 15) * 4;
#pragma unroll
    for (int it = 0; it < 4; ++it) {
        int r = rr + it * 16;
        float4 v = *(const float4*)(src + (size_t)r * DIMM + cc4);
        tile[r][cc4 + 0] = f2bf(v.x);
        tile[r][cc4 + 1] = f2bf(v.y);
        tile[r][cc4 + 2] = f2bf(v.z);
        tile[r][cc4 + 3] = f2bf(v.w);
    }
    __syncthreads();
#pragma unroll
    for (int it = 0; it < 2; ++it) {
        int u = t + it * 256;
        int c = u >> 3;                                // 0..63 (dim within tile)
        int kk = (u & 7) * 8;                          // 16B chunk along k
        ushort8v o;
#pragma unroll
        for (int e = 0; e < 8; ++e) o[e] = tile[kk + e][c];
        *(ushort8v*)(ctxT + ((size_t)b * DIMM + c0 + c) * KLEN + k0 + kk) = o;
    }
}

// ---------- softmax over rows of 4096: fp32 in-place + bf16 copy ----------
__global__ __launch_bounds__(256) void softmax_k(float* __restrict__ S,
                                                 unsigned short* __restrict__ Pb) {
    size_t row = blockIdx.x;
    float* p = S + row * KLEN;
    int t = threadIdx.x;
    int lane = t & 63, wv = t >> 6;
    float4 v[4];
    float mx = -3.0e38f;
#pragma unroll
    for (int i = 0; i < 4; ++i) {
        v[i] = *(const float4*)(p + i * 1024 + t * 4);
        mx = fmaxf(mx, fmaxf(fmaxf(v[i].x, v[i].y), fmaxf(v[i].z, v[i].w)));
    }
#pragma unroll
    for (int m = 32; m >= 1; m >>= 1) mx = fmaxf(mx, __shfl_xor(mx, m, 64));
    __shared__ float redm[4], reds[4];
    if (lane == 0) redm[wv] = mx;
    __syncthreads();
    mx = fmaxf(fmaxf(redm[0], redm[1]), fmaxf(redm[2], redm[3]));
    float sum = 0.f;
#pragma unroll
    for (int i = 0; i < 4; ++i) {
        v[i].x = __expf(v[i].x - mx); v[i].y = __expf(v[i].y - mx);
        v[i].z = __expf(v[i].z - mx); v[i].w = __expf(v[i].w - mx);
        sum += v[i].x + v[i].y + v[i].z + v[i].w;
    }
#pragma unroll
    for (int m = 32; m >= 1; m >>= 1) sum += __shfl_xor(sum, m, 64);
    if (lane == 0) reds[wv] = sum;
    __syncthreads();
    float inv = 1.0f / (reds[0] + reds[1] + reds[2] + reds[3]);
    unsigned short* pb = Pb + row * KLEN;
#pragma unroll
    for (int i = 0; i < 4; ++i) {
        float4 w;
        w.x = v[i].x * inv; w.y = v[i].y * inv; w.z = v[i].z * inv; w.w = v[i].w * inv;
        *(float4*)(p + i * 1024 + t * 4) = w;
        ushort4v h;
        h[0] = f2bf(w.x); h[1] = f2bf(w.y); h[2] = f2bf(w.z); h[3] = f2bf(w.w);
        *(ushort4v*)(pb + i * 1024 + t * 4) = h;
    }
}

// ---------- generic C = A * B^T GEMM (both operands K-major bf16), fp32 acc ----------
// BM=128 x BN tile, BK=64, 4 waves in 2x2; each wave 4 x (BN/32) MFMA 16x16x32 frags.
// XOR-swizzled LDS: global chunk (row,c) lives at physical slot c^(row&7).
//   Staging keeps LDS dests lane-ordered (global_load_lds constraint) and permutes
//   the GLOBAL chunk each lane fetches (row&7 == (tid>>3)&7 for all staging iters).
//   Reads use slot (c ^ (mlane&7)) since row&7 == mlane&7 -> 32 banks x 8 accesses
//   per wave instruction == conflict-free (was 16-way / 5.7x).
// EPI: 0 = store fp32; 1 = store bf16; 2 = tanh(x + bias[col]) fp32
// REMAP: QK split-bf16 virtual K=1536 over A=[Ah|Al](K=1024), B=[Bh|Bl](K=1024):
//   panels (Ah*Bh)+(Ah*Bl)+(Al*Bh)
template <int EPI, bool REMAP, int BN>
__global__ __launch_bounds__(256) void gemm_bt(
    const unsigned short* __restrict__ A,
    const unsigned short* __restrict__ Bm,
    float* __restrict__ Cf, unsigned short* __restrict__ Cb,
    const float* __restrict__ bias,
    int Ktiles, long lda, long ldb, long ldc,
    long a_bs, long b_bs, long c_bs) {
    constexpr int NF = BN / 32;                        // B frags per wave (2 or 4)
    __shared__ unsigned short sA[128 * 64];
    __shared__ unsigned short sB[BN * 64];
    const int tid = threadIdx.x;
    const int lane = tid & 63;
    const int wv = tid >> 6;
    const int wm = wv >> 1, wn = wv & 1;
    const int mlane = lane & 15, quad = lane >> 4;
    const unsigned short* Ab = A + (size_t)blockIdx.z * a_bs + (size_t)blockIdx.y * 128 * lda;
    const unsigned short* Bb = Bm + (size_t)blockIdx.z * b_bs + (size_t)blockIdx.x * BN * ldb;
    const int r8 = tid >> 3;          // 0..31: row within staging pass
    const int c8 = (tid & 7) << 3;    // LDS chunk offset (lane-ordered, unswizzled)
    const int cg = ((tid & 7) ^ ((tid >> 3) & 7)) << 3;   // swizzled GLOBAL chunk offset
    unsigned short* la = sA + r8 * 64 + c8;
    unsigned short* lb = sB + r8 * 64 + c8;

    floatx4 acc[4][NF] = {};

    for (int kt = 0; kt < Ktiles; ++kt) {
        long kv = (long)kt * 64;
        long ka = REMAP ? (kv >= 512 ? kv - 512 : kv) : kv;
        long kb = REMAP ? (kv >= 1024 ? kv - 1024 : kv) : kv;
        if (kt) __syncthreads();                       // protect LDS from overwrite
        const unsigned short* ga = Ab + (size_t)r8 * lda + ka + cg;
        const unsigned short* gb = Bb + (size_t)r8 * ldb + kb + cg;
#pragma unroll
        for (int it = 0; it < 4; ++it)
            gload16(ga + (size_t)(it * 32) * lda, la + it * 2048);
#pragma unroll
        for (int it = 0; it < BN / 32; ++it)
            gload16(gb + (size_t)(it * 32) * ldb, lb + it * 2048);
        __syncthreads();                               // drains vmcnt before barrier
#pragma unroll
        for (int s = 0; s < 2; ++s) {
            const int swz = (((s * 4 + quad) ^ (mlane & 7)) << 3);
            short8 af[4], bf[NF];
#pragma unroll
            for (int i = 0; i < 4; ++i)
                af[i] = *(const short8*)(sA + (wm * 64 + i * 16 + mlane) * 64 + swz);
#pragma unroll
            for (int j = 0; j < NF; ++j)
                bf[j] = *(const short8*)(sB + (wn * (BN / 2) + j * 16 + mlane) * 64 + swz);
#pragma unroll
            for (int i = 0; i < 4; ++i)
#pragma unroll
                for (int j = 0; j < NF; ++j)
                    acc[i][j] = __builtin_amdgcn_mfma_f32_16x16x32_bf16(af[i], bf[j], acc[i][j], 0, 0, 0);
        }
    }

    // epilogue: C/D layout col=lane&15, row=quad*4+reg
    size_t crow0 = (size_t)blockIdx.y * 128 + wm * 64 + quad * 4;
    size_t ccol0 = (size_t)blockIdx.x * BN + wn * (BN / 2) + mlane;
    size_t cbase = (size_t)blockIdx.z * c_bs;
#pragma unroll
    for (int i = 0; i < 4; ++i) {
#pragma unroll
        for (int j = 0; j < NF; ++j) {
            size_t gr = crow0 + i * 16;
            size_t gc = ccol0 + j * 16;
#pragma unroll
            for (int r = 0; r < 4; ++r) {
                float vv = acc[i][j][r];
                size_t off = cbase + (gr + r) * ldc + gc;
                if (EPI == 0) Cf[off] = vv;
                else if (EPI == 1) Cb[off] = f2bf(vv);
                else Cf[off] = tanhf(vv + bias[gc]);
            }
        }
    }
}

extern "C" void kernel_launch(void* const* d_in, const int* in_sizes, int n_in,
                              void* d_out, int out_size, void* d_ws, size_t ws_size,
                              hipStream_t stream) {
    (void)in_sizes; (void)n_in; (void)out_size; (void)ws_size;
    const float* outp = (const float*)d_in[0];   // [8,1024,512]
    const float* ctx  = (const float*)d_in[1];   // [8,4096,512]
    const float* W    = (const float*)d_in[2];   // [512,1024]  (already K-major for C=A*W^T)
    const float* bias = (const float*)d_in[3];   // [512]

    float* out0 = (float*)d_out;                              // [8,1024,512]
    float* attn = out0 + (size_t)NB * QLEN * DIMM;            // [8,1024,4096]

    unsigned char* w = (unsigned char*)d_ws;
    // Region plan (113 MiB peak, time-aliased):
    //   R1 (16 MiB): A2 = [outHi|outLo]          -> later: combined [mix | outHi]
    //   R2 (64 MiB): B2 = [ctxHi|ctxLo]          -> later: attn bf16
    //   R3 (32 MiB): ctxT hi bf16 [b,512,4096]
    //   R4 ( 1 MiB): W bf16
    unsigned short* R1 = (unsigned short*)(w);
    unsigned short* R2 = (unsigned short*)(w + (16ull << 20));
    unsigned short* R3 = (unsigned short*)(w + (80ull << 20));
    unsigned short* R4 = (unsigned short*)(w + (112ull << 20));

    // 1. prep
    split_k<<<4096, 256, 0, stream>>>(outp, R1);                     // output -> A2
    split_k<<<16384, 256, 0, stream>>>(ctx, R2);                     // context -> B2
    trans_hi<<<dim3(8, 64, 8), 256, 0, stream>>>(ctx, R3);           // context -> ctxT hi
    conv_hi<<<512, 256, 0, stream>>>(W, R4, 8, 1024, 0);             // W -> bf16

    // 2. QK^T split-bf16 (virtual K=1536) -> raw logits in attn region
    gemm_bt<0, true, 128><<<dim3(32, 8, 8), 256, 0, stream>>>(
        R1, R2, attn, nullptr, nullptr,
        24, 1024, 1024, 4096,
        (long)QLEN * 1024, (long)KLEN * 1024, (long)QLEN * KLEN);

    // 3. softmax rows: fp32 in-place + bf16 copy into R2 (B2 is dead)
    softmax_k<<<8192, 256, 0, stream>>>(attn, R2);

    // 4a. combined[:,512:] = outHi (R1's A2 is dead; rebuild as combined)
    conv_hi<<<4096, 256, 0, stream>>>(outp, R1, 7, 1024, 512);

    // 4b. PV: mix = attn_bf16 * ctxT^T -> combined[:,0:512] (bf16)
    //     BN=64 -> 512 blocks (2/CU) for latency hiding (was 256 = 1/CU)
    gemm_bt<1, false, 64><<<dim3(8, 8, 8), 256, 0, stream>>>(
        R2, R3, nullptr, R1, nullptr,
        64, 4096, 4096, 1024,
        (long)QLEN * KLEN, (long)DIMM * KLEN, (long)QLEN * 1024);

    // 5. out = tanh(combined * W^T + b)   BN=64 -> 512 blocks
    gemm_bt<2, false, 64><<<dim3(8, 64, 1), 256, 0, stream>>>(
        R1, R4, out0, nullptr, bias,
        16, 1024, 1024, 512, 0, 0, 0);
}

// Round 3
// 501.748 us; speedup vs baseline: 1.0827x; 1.0075x over previous
//
#include <hip/hip_runtime.h>
#include <math.h>

#define DIMM 512
#define NB 8
#define QLEN 1024
#define KLEN 4096

typedef __attribute__((ext_vector_type(16))) float floatx16;
typedef __attribute__((ext_vector_type(8))) short short8;     // 8 bf16 (4 VGPRs) MFMA frag
typedef __attribute__((ext_vector_type(4))) unsigned short ushort4v;
typedef __attribute__((ext_vector_type(8))) unsigned short ushort8v;

// ---------- bf16 helpers (bit-level, RNE) ----------
static __device__ __forceinline__ unsigned short f2bf(float f) {
    unsigned u = __builtin_bit_cast(unsigned, f);
    u += 0x7FFFu + ((u >> 16) & 1u);
    return (unsigned short)(u >> 16);
}
static __device__ __forceinline__ float bf2f(unsigned short h) {
    unsigned u = ((unsigned)h) << 16;
    return __builtin_bit_cast(float, u);
}
// register-lean tanh via __expf (libm tanhf is reg-heavy in the epilogue)
static __device__ __forceinline__ float fast_tanh(float x) {
    float e = __expf(-2.0f * fabsf(x));
    float t = (1.0f - e) / (1.0f + e);
    return copysignf(t, x);
}

// ---------- async global->LDS, 16B per lane ----------
static __device__ __forceinline__ void gload16(const unsigned short* g, unsigned short* l) {
    __builtin_amdgcn_global_load_lds(
        (__attribute__((address_space(1))) void*)const_cast<unsigned short*>(g),
        (__attribute__((address_space(3))) void*)l,
        16, 0, 0);
}

// ---------- prep: fp32 [R,512] -> bf16 [R,1024] = [hi | lo] ----------
__global__ __launch_bounds__(256) void split_k(const float* __restrict__ x,
                                               unsigned short* __restrict__ dst) {
    int idx = blockIdx.x * 256 + threadIdx.x;          // one float4 per thread
    float4 v = ((const float4*)x)[idx];
    int r = idx >> 7;                                  // 128 float4 per row (C=512)
    int c = (idx & 127) << 2;
    float f[4] = {v.x, v.y, v.z, v.w};
    ushort4v hi, lo;
#pragma unroll
    for (int e = 0; e < 4; ++e) {
        unsigned short h = f2bf(f[e]);
        hi[e] = h;
        lo[e] = f2bf(f[e] - bf2f(h));
    }
    unsigned short* row = dst + ((size_t)r << 10);     // row stride 1024
    *(ushort4v*)(row + c) = hi;
    *(ushort4v*)(row + 512 + c) = lo;
}

// ---------- prep: fp32 [R,C] -> bf16 at dst[r*ldd + off + c] ----------
__global__ __launch_bounds__(256) void conv_hi(const float* __restrict__ x,
                                               unsigned short* __restrict__ dst,
                                               int c4shift, int ldd, int off) {
    int idx = blockIdx.x * 256 + threadIdx.x;
    float4 v = ((const float4*)x)[idx];
    int r = idx >> c4shift;
    int c = (idx & ((1 << c4shift) - 1)) << 2;
    ushort4v hi;
    hi[0] = f2bf(v.x); hi[1] = f2bf(v.y); hi[2] = f2bf(v.z); hi[3] = f2bf(v.w);
    *(ushort4v*)(dst + (size_t)r * ldd + off + c) = hi;
}

// ---------- fused ctx prep: read ctx ONCE ->
//   hilo [b,4096, hi512|lo512] (QK B-operand) + ctxT [b,512,4096] bf16 hi (PV B) ----------
__global__ __launch_bounds__(256) void prep_ctx(const float* __restrict__ ctx,
                                                unsigned short* __restrict__ hilo,
                                                unsigned short* __restrict__ ctxT) {
    __shared__ unsigned short tile[64][66];            // +2 pad: spread banks
    int b = blockIdx.z;
    int c0 = blockIdx.x * 64;                          // dim index
    int k0 = blockIdx.y * 64;                          // seq index
    const float* src = ctx + ((size_t)b * KLEN + k0) * DIMM + c0;
    unsigned short* hl = hilo + ((size_t)b * KLEN + k0) * 1024 + c0;
    int t = threadIdx.x;
    int rr = t >> 4, cc4 = (t & 15) * 4;
#pragma unroll
    for (int it = 0; it < 4; ++it) {
        int r = rr + it * 16;
        float4 v = *(const float4*)(src + (size_t)r * DIMM + cc4);
        float f[4] = {v.x, v.y, v.z, v.w};
        ushort4v hi, lo;
#pragma unroll
        for (int e = 0; e < 4; ++e) {
            unsigned short h = f2bf(f[e]);
            hi[e] = h;
            lo[e] = f2bf(f[e] - bf2f(h));
            tile[r][cc4 + e] = h;
        }
        *(ushort4v*)(hl + (size_t)r * 1024 + cc4) = hi;
        *(ushort4v*)(hl + (size_t)r * 1024 + 512 + cc4) = lo;
    }
    __syncthreads();
#pragma unroll
    for (int it = 0; it < 2; ++it) {
        int u = t + it * 256;
        int c = u >> 3;                                // 0..63 (dim within tile)
        int kk = (u & 7) * 8;                          // 16B chunk along k
        ushort8v o;
#pragma unroll
        for (int e = 0; e < 8; ++e) o[e] = tile[kk + e][c];
        *(ushort8v*)(ctxT + ((size_t)b * DIMM + c0 + c) * KLEN + k0 + kk) = o;
    }
}

// ---------- softmax over rows of 4096: fp32 in-place + bf16 copy ----------
__global__ __launch_bounds__(256) void softmax_k(float* __restrict__ S,
                                                 unsigned short* __restrict__ Pb) {
    size_t row = blockIdx.x;
    float* p = S + row * KLEN;
    int t = threadIdx.x;
    int lane = t & 63, wv = t >> 6;
    float4 v[4];
    float mx = -3.0e38f;
#pragma unroll
    for (int i = 0; i < 4; ++i) {
        v[i] = *(const float4*)(p + i * 1024 + t * 4);
        mx = fmaxf(mx, fmaxf(fmaxf(v[i].x, v[i].y), fmaxf(v[i].z, v[i].w)));
    }
#pragma unroll
    for (int m = 32; m >= 1; m >>= 1) mx = fmaxf(mx, __shfl_xor(mx, m, 64));
    __shared__ float redm[4], reds[4];
    if (lane == 0) redm[wv] = mx;
    __syncthreads();
    mx = fmaxf(fmaxf(redm[0], redm[1]), fmaxf(redm[2], redm[3]));
    float sum = 0.f;
#pragma unroll
    for (int i = 0; i < 4; ++i) {
        v[i].x = __expf(v[i].x - mx); v[i].y = __expf(v[i].y - mx);
        v[i].z = __expf(v[i].z - mx); v[i].w = __expf(v[i].w - mx);
        sum += v[i].x + v[i].y + v[i].z + v[i].w;
    }
#pragma unroll
    for (int m = 32; m >= 1; m >>= 1) sum += __shfl_xor(sum, m, 64);
    if (lane == 0) reds[wv] = sum;
    __syncthreads();
    float inv = 1.0f / (reds[0] + reds[1] + reds[2] + reds[3]);
    unsigned short* pb = Pb + row * KLEN;
#pragma unroll
    for (int i = 0; i < 4; ++i) {
        float4 w;
        w.x = v[i].x * inv; w.y = v[i].y * inv; w.z = v[i].z * inv; w.w = v[i].w * inv;
        *(float4*)(p + i * 1024 + t * 4) = w;
        ushort4v h;
        h[0] = f2bf(w.x); h[1] = f2bf(w.y); h[2] = f2bf(w.z); h[3] = f2bf(w.w);
        *(ushort4v*)(pb + i * 1024 + t * 4) = h;
    }
}

// ---------- generic C = A * B^T GEMM (both operands K-major bf16), fp32 acc ----------
// BM=128 x BN tile, BK=64, 4 waves in 2x2; each wave 2 x (BN/64) frags of 32x32x16 MFMA.
// 32x32x16 (vs 16x16x32): same 64 acc regs but half the live A/B frags (16 vs 32 VGPRs)
// and half the MFMA issue count at a 15% higher ubench ceiling. Combined with
// __launch_bounds__(256,4) this targets <=128 unified regs -> 4 blocks/CU (was 136 regs
// -> 2 blocks/CU per the 64/128/256 wave-occupancy steps; measured Occupancy 27%).
// XOR-swizzled LDS (conflict-free: 8 lanes/chunk = wave64 minimum):
//   global chunk (row,c) at physical slot c^(row&7); staging keeps LDS dests
//   lane-ordered (global_load_lds constraint) and permutes the GLOBAL chunk per lane.
// A-frag (32x32x16): lane holds A[m=lane&31][k=(lane>>5)*8+j]; C/D: col=lane&31,
//   row=(reg&3)+8*(reg>>2)+4*(lane>>5)  [measured m74/m101].
// EPI: 0 = store fp32; 1 = store bf16; 2 = tanh(x + bias[col]) fp32
// REMAP: QK split-bf16 virtual K=1536 over A=[Ah|Al](K=1024), B=[Bh|Bl](K=1024):
//   panels (Ah*Bh)+(Ah*Bl)+(Al*Bh)
template <int EPI, bool REMAP, int BN>
__global__ __launch_bounds__(256, 4) void gemm_bt(
    const unsigned short* __restrict__ A,
    const unsigned short* __restrict__ Bm,
    float* __restrict__ Cf, unsigned short* __restrict__ Cb,
    const float* __restrict__ bias,
    int Ktiles, long lda, long ldb, long ldc,
    long a_bs, long b_bs, long c_bs) {
    constexpr int NJ = BN / 64;                        // 32-wide B frags per wave (2 or 1)
    __shared__ unsigned short sA[128 * 64];
    __shared__ unsigned short sB[BN * 64];
    const int tid = threadIdx.x;
    const int lane = tid & 63;
    const int wv = tid >> 6;
    const int wm = wv >> 1, wn = wv & 1;
    const int m32 = lane & 31, half = lane >> 5;
    const unsigned short* Ab = A + (size_t)blockIdx.z * a_bs + (size_t)blockIdx.y * 128 * lda;
    const unsigned short* Bb = Bm + (size_t)blockIdx.z * b_bs + (size_t)blockIdx.x * BN * ldb;
    const int r8 = tid >> 3;          // 0..31: row within staging pass
    const int c8 = (tid & 7) << 3;    // LDS chunk offset (lane-ordered, unswizzled)
    const int cg = ((tid & 7) ^ ((tid >> 3) & 7)) << 3;   // swizzled GLOBAL chunk offset
    unsigned short* la = sA + r8 * 64 + c8;
    unsigned short* lb = sB + r8 * 64 + c8;

    floatx16 acc[2][NJ] = {};

    for (int kt = 0; kt < Ktiles; ++kt) {
        long kv = (long)kt * 64;
        long ka = REMAP ? (kv >= 512 ? kv - 512 : kv) : kv;
        long kb = REMAP ? (kv >= 1024 ? kv - 1024 : kv) : kv;
        if (kt) __syncthreads();                       // protect LDS from overwrite
        const unsigned short* ga = Ab + (size_t)r8 * lda + ka + cg;
        const unsigned short* gb = Bb + (size_t)r8 * ldb + kb + cg;
#pragma unroll
        for (int it = 0; it < 4; ++it)
            gload16(ga + (size_t)(it * 32) * lda, la + it * 2048);
#pragma unroll
        for (int it = 0; it < BN / 32; ++it)
            gload16(gb + (size_t)(it * 32) * ldb, lb + it * 2048);
        __syncthreads();                               // drains vmcnt before barrier
#pragma unroll
        for (int s = 0; s < 4; ++s) {
            const int swz = (((s * 2 + half) ^ (lane & 7)) << 3);
            short8 af[2], bf[NJ];
#pragma unroll
            for (int i = 0; i < 2; ++i)
                af[i] = *(const short8*)(sA + (wm * 64 + i * 32 + m32) * 64 + swz);
#pragma unroll
            for (int j = 0; j < NJ; ++j)
                bf[j] = *(const short8*)(sB + (wn * (BN / 2) + j * 32 + m32) * 64 + swz);
#pragma unroll
            for (int i = 0; i < 2; ++i)
#pragma unroll
                for (int j = 0; j < NJ; ++j)
                    acc[i][j] = __builtin_amdgcn_mfma_f32_32x32x16_bf16(af[i], bf[j], acc[i][j], 0, 0, 0);
        }
    }

    // epilogue: C/D layout col=lane&31, row=(reg&3)+8*(reg>>2)+4*half
    size_t crow0 = (size_t)blockIdx.y * 128 + wm * 64 + half * 4;
    size_t ccol0 = (size_t)blockIdx.x * BN + wn * (BN / 2) + m32;
    size_t cbase = (size_t)blockIdx.z * c_bs;
#pragma unroll
    for (int i = 0; i < 2; ++i) {
#pragma unroll
        for (int j = 0; j < NJ; ++j) {
            size_t gc = ccol0 + j * 32;
#pragma unroll
            for (int r2 = 0; r2 < 4; ++r2) {
#pragma unroll
                for (int r1 = 0; r1 < 4; ++r1) {
                    float vv = acc[i][j][r2 * 4 + r1];
                    size_t gr = crow0 + i * 32 + r2 * 8 + r1;
                    size_t off = cbase + gr * ldc + gc;
                    if (EPI == 0) Cf[off] = vv;
                    else if (EPI == 1) Cb[off] = f2bf(vv);
                    else Cf[off] = fast_tanh(vv + bias[gc]);
                }
            }
        }
    }
}

extern "C" void kernel_launch(void* const* d_in, const int* in_sizes, int n_in,
                              void* d_out, int out_size, void* d_ws, size_t ws_size,
                              hipStream_t stream) {
    (void)in_sizes; (void)n_in; (void)out_size; (void)ws_size;
    const float* outp = (const float*)d_in[0];   // [8,1024,512]
    const float* ctx  = (const float*)d_in[1];   // [8,4096,512]
    const float* W    = (const float*)d_in[2];   // [512,1024]  (already K-major for C=A*W^T)
    const float* bias = (const float*)d_in[3];   // [512]

    float* out0 = (float*)d_out;                              // [8,1024,512]
    float* attn = out0 + (size_t)NB * QLEN * DIMM;            // [8,1024,4096]

    unsigned char* w = (unsigned char*)d_ws;
    // Region plan (113 MiB peak, time-aliased):
    //   R1 (16 MiB): A2 = [outHi|outLo]          -> later: combined [mix | outHi]
    //   R2 (64 MiB): B2 = [ctxHi|ctxLo]          -> later: attn bf16
    //   R3 (32 MiB): ctxT hi bf16 [b,512,4096]
    //   R4 ( 1 MiB): W bf16
    unsigned short* R1 = (unsigned short*)(w);
    unsigned short* R2 = (unsigned short*)(w + (16ull << 20));
    unsigned short* R3 = (unsigned short*)(w + (80ull << 20));
    unsigned short* R4 = (unsigned short*)(w + (112ull << 20));

    // 1. prep (ctx read once: hilo + transpose fused)
    split_k<<<4096, 256, 0, stream>>>(outp, R1);                     // output -> A2
    prep_ctx<<<dim3(8, 64, 8), 256, 0, stream>>>(ctx, R2, R3);       // ctx -> B2 + ctxT
    conv_hi<<<512, 256, 0, stream>>>(W, R4, 8, 1024, 0);             // W -> bf16

    // 2. QK^T split-bf16 (virtual K=1536) -> raw logits in attn region
    gemm_bt<0, true, 128><<<dim3(32, 8, 8), 256, 0, stream>>>(
        R1, R2, attn, nullptr, nullptr,
        24, 1024, 1024, 4096,
        (long)QLEN * 1024, (long)KLEN * 1024, (long)QLEN * KLEN);

    // 3. softmax rows: fp32 in-place + bf16 copy into R2 (B2 is dead)
    softmax_k<<<8192, 256, 0, stream>>>(attn, R2);

    // 4a. combined[:,512:] = outHi (R1's A2 is dead; rebuild as combined)
    conv_hi<<<4096, 256, 0, stream>>>(outp, R1, 7, 1024, 512);

    // 4b. PV: mix = attn_bf16 * ctxT^T -> combined[:,0:512] (bf16)
    gemm_bt<1, false, 64><<<dim3(8, 8, 8), 256, 0, stream>>>(
        R2, R3, nullptr, R1, nullptr,
        64, 4096, 4096, 1024,
        (long)QLEN * KLEN, (long)DIMM * KLEN, (long)QLEN * 1024);

    // 5. out = tanh(combined * W^T + b)
    gemm_bt<2, false, 64><<<dim3(8, 64, 1), 256, 0, stream>>>(
        R1, R4, out0, nullptr, bias,
        16, 1024, 1024, 512, 0, 0, 0);
}

// Round 4
// 476.971 us; speedup vs baseline: 1.1389x; 1.0519x over previous
//
#include <hip/hip_runtime.h>
#include <math.h>

#define DIMM 512
#define NB 8
#define QLEN 1024
#define KLEN 4096

typedef __attribute__((ext_vector_type(4))) float floatx4;
typedef __attribute__((ext_vector_type(8))) short short8;     // 8 bf16 (4 VGPRs) MFMA frag
typedef __attribute__((ext_vector_type(4))) unsigned short ushort4v;
typedef __attribute__((ext_vector_type(8))) unsigned short ushort8v;

// ---------- bf16 helpers (bit-level, RNE) ----------
static __device__ __forceinline__ unsigned short f2bf(float f) {
    unsigned u = __builtin_bit_cast(unsigned, f);
    u += 0x7FFFu + ((u >> 16) & 1u);
    return (unsigned short)(u >> 16);
}
static __device__ __forceinline__ float bf2f(unsigned short h) {
    unsigned u = ((unsigned)h) << 16;
    return __builtin_bit_cast(float, u);
}
// register-lean tanh via __expf
static __device__ __forceinline__ float fast_tanh(float x) {
    float e = __expf(-2.0f * fabsf(x));
    float t = (1.0f - e) / (1.0f + e);
    return copysignf(t, x);
}

// ---------- async global->LDS, 16B per lane ----------
static __device__ __forceinline__ void gload16(const unsigned short* g, unsigned short* l) {
    __builtin_amdgcn_global_load_lds(
        (__attribute__((address_space(1))) void*)const_cast<unsigned short*>(g),
        (__attribute__((address_space(3))) void*)l,
        16, 0, 0);
}

// ---------- prep: fp32 [R,512] -> bf16 [R,1024] = [lo | hi] ----------
// [lo|hi] (not [hi|lo]) so that after QK, cols 512:1024 ARE combined[:,512:]=output_hi
// in place -> the former conv_hi(outp) dispatch is deleted.
__global__ __launch_bounds__(256) void split_k(const float* __restrict__ x,
                                               unsigned short* __restrict__ dst) {
    int idx = blockIdx.x * 256 + threadIdx.x;          // one float4 per thread
    float4 v = ((const float4*)x)[idx];
    int r = idx >> 7;                                  // 128 float4 per row (C=512)
    int c = (idx & 127) << 2;
    float f[4] = {v.x, v.y, v.z, v.w};
    ushort4v hi, lo;
#pragma unroll
    for (int e = 0; e < 4; ++e) {
        unsigned short h = f2bf(f[e]);
        hi[e] = h;
        lo[e] = f2bf(f[e] - bf2f(h));
    }
    unsigned short* row = dst + ((size_t)r << 10);     // row stride 1024
    *(ushort4v*)(row + c) = lo;
    *(ushort4v*)(row + 512 + c) = hi;
}

// ---------- prep: fp32 [R,C] -> bf16 at dst[r*ldd + off + c] ----------
__global__ __launch_bounds__(256) void conv_hi(const float* __restrict__ x,
                                               unsigned short* __restrict__ dst,
                                               int c4shift, int ldd, int off) {
    int idx = blockIdx.x * 256 + threadIdx.x;
    float4 v = ((const float4*)x)[idx];
    int r = idx >> c4shift;
    int c = (idx & ((1 << c4shift) - 1)) << 2;
    ushort4v hi;
    hi[0] = f2bf(v.x); hi[1] = f2bf(v.y); hi[2] = f2bf(v.z); hi[3] = f2bf(v.w);
    *(ushort4v*)(dst + (size_t)r * ldd + off + c) = hi;
}

// ---------- fused ctx prep: read ctx ONCE ->
//   hilo [b,4096, hi512|lo512] (QK B-operand) + ctxT [b,512,4096] bf16 hi (PV B) ----------
__global__ __launch_bounds__(256) void prep_ctx(const float* __restrict__ ctx,
                                                unsigned short* __restrict__ hilo,
                                                unsigned short* __restrict__ ctxT) {
    __shared__ unsigned short tile[64][66];            // +2 pad: spread banks
    int b = blockIdx.z;
    int c0 = blockIdx.x * 64;                          // dim index
    int k0 = blockIdx.y * 64;                          // seq index
    const float* src = ctx + ((size_t)b * KLEN + k0) * DIMM + c0;
    unsigned short* hl = hilo + ((size_t)b * KLEN + k0) * 1024 + c0;
    int t = threadIdx.x;
    int rr = t >> 4, cc4 = (t & 15) * 4;
#pragma unroll
    for (int it = 0; it < 4; ++it) {
        int r = rr + it * 16;
        float4 v = *(const float4*)(src + (size_t)r * DIMM + cc4);
        float f[4] = {v.x, v.y, v.z, v.w};
        ushort4v hi, lo;
#pragma unroll
        for (int e = 0; e < 4; ++e) {
            unsigned short h = f2bf(f[e]);
            hi[e] = h;
            lo[e] = f2bf(f[e] - bf2f(h));
            tile[r][cc4 + e] = h;
        }
        *(ushort4v*)(hl + (size_t)r * 1024 + cc4) = hi;
        *(ushort4v*)(hl + (size_t)r * 1024 + 512 + cc4) = lo;
    }
    __syncthreads();
#pragma unroll
    for (int it = 0; it < 2; ++it) {
        int u = t + it * 256;
        int c = u >> 3;                                // 0..63 (dim within tile)
        int kk = (u & 7) * 8;                          // 16B chunk along k
        ushort8v o;
#pragma unroll
        for (int e = 0; e < 8; ++e) o[e] = tile[kk + e][c];
        *(ushort8v*)(ctxT + ((size_t)b * DIMM + c0 + c) * KLEN + k0 + kk) = o;
    }
}

// ---------- softmax over rows of 4096: fp32 in-place + bf16 copy ----------
__global__ __launch_bounds__(256) void softmax_k(float* __restrict__ S,
                                                 unsigned short* __restrict__ Pb) {
    size_t row = blockIdx.x;
    float* p = S + row * KLEN;
    int t = threadIdx.x;
    int lane = t & 63, wv = t >> 6;
    float4 v[4];
    float mx = -3.0e38f;
#pragma unroll
    for (int i = 0; i < 4; ++i) {
        v[i] = *(const float4*)(p + i * 1024 + t * 4);
        mx = fmaxf(mx, fmaxf(fmaxf(v[i].x, v[i].y), fmaxf(v[i].z, v[i].w)));
    }
#pragma unroll
    for (int m = 32; m >= 1; m >>= 1) mx = fmaxf(mx, __shfl_xor(mx, m, 64));
    __shared__ float redm[4], reds[4];
    if (lane == 0) redm[wv] = mx;
    __syncthreads();
    mx = fmaxf(fmaxf(redm[0], redm[1]), fmaxf(redm[2], redm[3]));
    float sum = 0.f;
#pragma unroll
    for (int i = 0; i < 4; ++i) {
        v[i].x = __expf(v[i].x - mx); v[i].y = __expf(v[i].y - mx);
        v[i].z = __expf(v[i].z - mx); v[i].w = __expf(v[i].w - mx);
        sum += v[i].x + v[i].y + v[i].z + v[i].w;
    }
#pragma unroll
    for (int m = 32; m >= 1; m >>= 1) sum += __shfl_xor(sum, m, 64);
    if (lane == 0) reds[wv] = sum;
    __syncthreads();
    float inv = 1.0f / (reds[0] + reds[1] + reds[2] + reds[3]);
    unsigned short* pb = Pb + row * KLEN;
#pragma unroll
    for (int i = 0; i < 4; ++i) {
        float4 w;
        w.x = v[i].x * inv; w.y = v[i].y * inv; w.z = v[i].z * inv; w.w = v[i].w * inv;
        *(float4*)(p + i * 1024 + t * 4) = w;
        ushort4v h;
        h[0] = f2bf(w.x); h[1] = f2bf(w.y); h[2] = f2bf(w.z); h[3] = f2bf(w.w);
        *(ushort4v*)(pb + i * 1024 + t * 4) = h;
    }
}

// ---------- generic C = A * B^T GEMM (both operands K-major bf16), fp32 acc ----------
// BM=128 x BN tile, BK=64, 4 waves 2x2; wave = 4 x (BN/32) frags of 16x16x32 MFMA.
// 16x16x32 read pattern (16 rows x 2 chunks per b128) is the 0-conflict one:
//   R3's 32x32x16 spanned 32 rows/read -> inherent 4-way conflict (8-slot XOR can't
//   spread 32 rows; measured 1.26e7). R2 measured 0 with this exact pattern.
// Occupancy: __launch_bounds__(256,4) + streamed bf frags (live = 64 acc + 16 af + 4 bf)
//   targets <=128 unified regs -> 4 blocks/CU (R2 was 136 -> 2 blocks/CU).
// XOR-swizzled LDS: global chunk (row,c) at physical slot c^(row&7); staging keeps LDS
//   dests lane-ordered (global_load_lds constraint), permutes the GLOBAL chunk per lane.
// EPI: 0 = store fp32; 1 = store bf16; 2 = tanh(x + bias[col]) fp32
// REMAP (QK split-bf16, virtual K=1536): A=[Al|Ah] (lo 0:512, hi 512:1024),
//   B=[Bh|Bl] (hi 0:512, lo 512:1024). Panels Ah*Bh + Ah*Bl + Al*Bh:
//   ka = kv<512 ? kv+512 : (kv<1024 ? kv : kv-1024);  kb = kv<1024 ? kv : kv-1024
template <int EPI, bool REMAP, int BN>
__global__ __launch_bounds__(256, 4) void gemm_bt(
    const unsigned short* __restrict__ A,
    const unsigned short* __restrict__ Bm,
    float* __restrict__ Cf, unsigned short* __restrict__ Cb,
    const float* __restrict__ bias,
    int Ktiles, long lda, long ldb, long ldc,
    long a_bs, long b_bs, long c_bs) {
    constexpr int NF = BN / 32;                        // B frags per wave (4 or 2)
    __shared__ unsigned short sA[128 * 64];
    __shared__ unsigned short sB[BN * 64];
    const int tid = threadIdx.x;
    const int lane = tid & 63;
    const int wv = tid >> 6;
    const int wm = wv >> 1, wn = wv & 1;
    const int mlane = lane & 15, quad = lane >> 4;
    const unsigned short* Ab = A + (size_t)blockIdx.z * a_bs + (size_t)blockIdx.y * 128 * lda;
    const unsigned short* Bb = Bm + (size_t)blockIdx.z * b_bs + (size_t)blockIdx.x * BN * ldb;
    const int r8 = tid >> 3;          // 0..31: row within staging pass
    const int c8 = (tid & 7) << 3;    // LDS chunk offset (lane-ordered, unswizzled)
    const int cg = ((tid & 7) ^ ((tid >> 3) & 7)) << 3;   // swizzled GLOBAL chunk offset
    unsigned short* la = sA + r8 * 64 + c8;
    unsigned short* lb = sB + r8 * 64 + c8;

    floatx4 acc[4][NF] = {};

    for (int kt = 0; kt < Ktiles; ++kt) {
        long kv = (long)kt * 64;
        long ka = kv, kb = kv;
        if (REMAP) {
            ka = kv < 512 ? kv + 512 : (kv < 1024 ? kv : kv - 1024);
            kb = kv < 1024 ? kv : kv - 1024;
        }
        if (kt) __syncthreads();                       // protect LDS from overwrite
        const unsigned short* ga = Ab + (size_t)r8 * lda + ka + cg;
        const unsigned short* gb = Bb + (size_t)r8 * ldb + kb + cg;
#pragma unroll
        for (int it = 0; it < 4; ++it)
            gload16(ga + (size_t)(it * 32) * lda, la + it * 2048);
#pragma unroll
        for (int it = 0; it < BN / 32; ++it)
            gload16(gb + (size_t)(it * 32) * ldb, lb + it * 2048);
        __syncthreads();                               // drains vmcnt before barrier
#pragma unroll
        for (int s = 0; s < 2; ++s) {
            const int swz = (((s * 4 + quad) ^ (mlane & 7)) << 3);
            short8 af[4];
#pragma unroll
            for (int i = 0; i < 4; ++i)
                af[i] = *(const short8*)(sA + (wm * 64 + i * 16 + mlane) * 64 + swz);
#pragma unroll
            for (int j = 0; j < NF; ++j) {             // stream bf: keeps live regs low
                short8 bfj = *(const short8*)(sB + (wn * (BN / 2) + j * 16 + mlane) * 64 + swz);
#pragma unroll
                for (int i = 0; i < 4; ++i)
                    acc[i][j] = __builtin_amdgcn_mfma_f32_16x16x32_bf16(af[i], bfj, acc[i][j], 0, 0, 0);
            }
        }
    }

    // epilogue: C/D layout col=lane&15, row=quad*4+reg
    size_t crow0 = (size_t)blockIdx.y * 128 + wm * 64 + quad * 4;
    size_t ccol0 = (size_t)blockIdx.x * BN + wn * (BN / 2) + mlane;
    size_t cbase = (size_t)blockIdx.z * c_bs;
#pragma unroll
    for (int i = 0; i < 4; ++i) {
#pragma unroll
        for (int j = 0; j < NF; ++j) {
            size_t gr = crow0 + i * 16;
            size_t gc = ccol0 + j * 16;
#pragma unroll
            for (int r = 0; r < 4; ++r) {
                float vv = acc[i][j][r];
                size_t off = cbase + (gr + r) * ldc + gc;
                if (EPI == 0) Cf[off] = vv;
                else if (EPI == 1) Cb[off] = f2bf(vv);
                else Cf[off] = fast_tanh(vv + bias[gc]);
            }
        }
    }
}

extern "C" void kernel_launch(void* const* d_in, const int* in_sizes, int n_in,
                              void* d_out, int out_size, void* d_ws, size_t ws_size,
                              hipStream_t stream) {
    (void)in_sizes; (void)n_in; (void)out_size; (void)ws_size;
    const float* outp = (const float*)d_in[0];   // [8,1024,512]
    const float* ctx  = (const float*)d_in[1];   // [8,4096,512]
    const float* W    = (const float*)d_in[2];   // [512,1024]  (already K-major for C=A*W^T)
    const float* bias = (const float*)d_in[3];   // [512]

    float* out0 = (float*)d_out;                              // [8,1024,512]
    float* attn = out0 + (size_t)NB * QLEN * DIMM;            // [8,1024,4096]

    unsigned char* w = (unsigned char*)d_ws;
    // Region plan (113 MiB peak, time-aliased):
    //   R1 (16 MiB): A2 = [outLo|outHi]          -> later: combined [mix | outHi] (hi in place)
    //   R2 (64 MiB): B2 = [ctxHi|ctxLo]          -> later: attn bf16
    //   R3 (32 MiB): ctxT hi bf16 [b,512,4096]
    //   R4 ( 1 MiB): W bf16
    unsigned short* R1 = (unsigned short*)(w);
    unsigned short* R2 = (unsigned short*)(w + (16ull << 20));
    unsigned short* R3 = (unsigned short*)(w + (80ull << 20));
    unsigned short* R4 = (unsigned short*)(w + (112ull << 20));

    // 1. prep (ctx read once: hilo + transpose fused)
    split_k<<<4096, 256, 0, stream>>>(outp, R1);                     // output -> [lo|hi]
    prep_ctx<<<dim3(8, 64, 8), 256, 0, stream>>>(ctx, R2, R3);       // ctx -> B2 + ctxT
    conv_hi<<<512, 256, 0, stream>>>(W, R4, 8, 1024, 0);             // W -> bf16

    // 2. QK^T split-bf16 (virtual K=1536) -> raw logits in attn region
    gemm_bt<0, true, 128><<<dim3(32, 8, 8), 256, 0, stream>>>(
        R1, R2, attn, nullptr, nullptr,
        24, 1024, 1024, 4096,
        (long)QLEN * 1024, (long)KLEN * 1024, (long)QLEN * KLEN);

    // 3. softmax rows: fp32 in-place + bf16 copy into R2 (B2 is dead)
    softmax_k<<<8192, 256, 0, stream>>>(attn, R2);

    // 4. PV: mix = attn_bf16 * ctxT^T -> combined[:,0:512] (bf16, overwrites dead outLo)
    gemm_bt<1, false, 64><<<dim3(8, 8, 8), 256, 0, stream>>>(
        R2, R3, nullptr, R1, nullptr,
        64, 4096, 4096, 1024,
        (long)QLEN * KLEN, (long)DIMM * KLEN, (long)QLEN * 1024);

    // 5. out = tanh(combined * W^T + b)   (combined = [mix | outHi] already assembled)
    gemm_bt<2, false, 64><<<dim3(8, 64, 1), 256, 0, stream>>>(
        R1, R4, out0, nullptr, bias,
        16, 1024, 1024, 512, 0, 0, 0);
}